// Round 17
// baseline (209.438 us; speedup 1.0000x reference)
//
#include <hip/hip_runtime.h>
#include <hip/hip_bf16.h>
#include <stdint.h>

typedef __bf16 bf16x8 __attribute__((ext_vector_type(8)));
typedef float  f32x4  __attribute__((ext_vector_type(4)));
typedef unsigned uint4v __attribute__((ext_vector_type(4)));
using bf16 = __hip_bfloat16;

#define NNODES 8192
#define FIN    8256      // 8192 + 64
#define NCOL   192       // 128 (W1) + 64 (W2 top)
#define KT32   258       // 8256 / 32
#define BMB    128       // rows per block (4 waves x 32 rows each)

// ---- workspace layout (bytes) ----
enum : size_t {
  WCT_OFF  = 0,            // bf16 wctf [258][12][64][8]  3,170,304
  CNT_OFF  = 3170304,      // int  [8192]
  OFF_OFF  = 3203072,      // int  [8193]
  CUR_OFF  = 3236096,      // int  [8192]
  DNV_OFF  = 3268864,      // f32  [8192]
  CSR_OFF  = 3301632,      // int  [262144]
  H1_OFF   = 4350208,      // bf16 [8192][128]
  HX2_OFF  = 8544512,      // f32  [8192][64]
  RU_OFF   = 10641664,     // f32  [8192][128]
  H2_OFF   = 14835968,     // bf16 [8192][64]
  YP_OFF   = 16933120,     // f32  [ksplit][8192][192]
  YP_SLICE = 6291456
};

__global__ void k_zero_i(int* p, int n) {
  int i = blockIdx.x * 256 + threadIdx.x;
  if (i < n) p[i] = 0;
}

__global__ void k_out_zero(float* out) {
  int i = blockIdx.x * 256 + threadIdx.x;
  if (i < NNODES * 64) out[i] = 0.f;   // diagnostic signature if ws too small
}

// Build B in MFMA-fragment order: wctf[((t*12+nf)*64+lane)*8+j] =
//   Wc[k = t*32 + (lane>>4)*8 + j][col = nf*16 + (lane&15)]
__global__ void k_prep_wctf(const float* __restrict__ W1, const float* __restrict__ W2,
                            bf16* __restrict__ wctf) {
  int gid = blockIdx.x * 256 + threadIdx.x;
  if (gid >= KT32 * 12 * 64) return;
  int t = gid / 768;
  int rem = gid - t * 768;
  int nf = rem >> 6, lane = rem & 63;
  int col = nf * 16 + (lane & 15);
  int k0 = t * 32 + (lane >> 4) * 8;
  union { bf16 h[8]; uint4 v; } u;
#pragma unroll
  for (int j = 0; j < 8; ++j) {
    int k = k0 + j;
    float v;
    if (col < 128)      v = W1[(size_t)k * 128 + col];
    else if (k < 8192)  v = W2[(size_t)k * 64 + (col - 128)];
    else                v = 0.f;
    u.h[j] = __float2bfloat16(v);
  }
  *(uint4*)(wctf + (size_t)gid * 8) = u.v;
}

__global__ void k_hist(const int* __restrict__ ei, int E, int* cnt) {
  int e = blockIdx.x * 256 + threadIdx.x;
  if (e < E) atomicAdd(&cnt[ei[E + e]], 1);
}

__global__ void k_scan(const int* __restrict__ cnt, int* __restrict__ offs,
                       int* __restrict__ cur, float* __restrict__ dinv) {
  __shared__ int part[256];
  int tid = threadIdx.x;
  int base = tid * 32;
  int s = 0;
#pragma unroll
  for (int j = 0; j < 32; j++) s += cnt[base + j];
  part[tid] = s;
  __syncthreads();
  for (int off = 1; off < 256; off <<= 1) {
    int a = (tid >= off) ? part[tid - off] : 0;
    __syncthreads();
    part[tid] += a;
    __syncthreads();
  }
  int run = (tid == 0) ? 0 : part[tid - 1];
  for (int j = 0; j < 32; j++) {
    int c = cnt[base + j];
    offs[base + j] = run;
    cur[base + j]  = run;
    dinv[base + j] = rsqrtf((float)(c + 1));
    run += c;
  }
  if (tid == 255) offs[NNODES] = run;
}

__global__ void k_fill(const int* __restrict__ ei, int E, int* cur, int* __restrict__ csr) {
  int e = blockIdx.x * 256 + threadIdx.x;
  if (e < E) {
    int d = ei[E + e];
    int p = atomicAdd(&cur[d], 1);
    csr[p] = ei[e];
  }
}

__device__ __forceinline__ bf16x8 pack8(float4 a, float4 b) {
  union { bf16 h[8]; bf16x8 v; } u;
  u.h[0] = __float2bfloat16(a.x); u.h[1] = __float2bfloat16(a.y);
  u.h[2] = __float2bfloat16(a.z); u.h[3] = __float2bfloat16(a.w);
  u.h[4] = __float2bfloat16(b.x); u.h[5] = __float2bfloat16(b.y);
  u.h[6] = __float2bfloat16(b.z); u.h[7] = __float2bfloat16(b.w);
  return u.v;
}

union F4 { uint4v u; float4 f; bf16x8 h; };

__device__ __forceinline__ void gld16(void* ldsdst, const void* gsrc) {
  __builtin_amdgcn_global_load_lds(
      (__attribute__((address_space(1))) void*)gsrc,
      (__attribute__((address_space(3))) void*)ldsdst, 16, 0, 0);
}

// C = [x | hidden] @ Wc : M=8192, N=192, K=8256
// R16 pipeline minus A-in-LDS: A (HBM stream) goes global->REGISTER (asm, P/Q
// ping-pong) so the DS pipe carries only B (12KB DMA-write + 48KB read per
// block-iter, was 92KB) — isolates the DMA-vs-ds_read contention hypothesis.
// B: triple-buffered LDS via global_load_lds, counted per-thread vmcnt
// (iter i issues B(i+2)[3] then A(i+1)[4]; need A(i),B(i) -> vmcnt(7)/4/0),
// asm s_barrier (no legalizer drain), asm ds_read + lgkmcnt + sched_barrier.
__global__ __launch_bounds__(256, 2) void k_gemm(const float* __restrict__ x,
                                                 const float* __restrict__ hid,
                                                 const bf16* __restrict__ wctf,
                                                 float* __restrict__ yp,
                                                 bf16* __restrict__ h1d,
                                                 float* __restrict__ hx2d,
                                                 int tpc) {
  __shared__ __align__(1024) unsigned char smem[36864];  // B: 3 x 12KB
  const int tid = threadIdx.x;
  const int lane = tid & 63, w = tid >> 6;
  const int rl = lane & 15, g = lane >> 4;
  const int m0 = blockIdx.x * BMB;
  const int r0 = m0 + w * 32 + rl, r1 = r0 + 16;
  const int chunk = blockIdx.y;
  const int t_lo = chunk * tpc;
  const int t_hi = (t_lo + tpc > KT32) ? KT32 : (t_lo + tpc);
  const int nt = t_hi - t_lo;
  if (nt <= 0) return;

  const float* a0x = x + (size_t)r0 * 8192 + g * 8;
  const float* a1x = x + (size_t)r1 * 8192 + g * 8;
  const float* a0h = hid + (size_t)r0 * 64 + g * 8;
  const float* a1h = hid + (size_t)r1 * 64 + g * 8;

#define STAGE_B(buf, t) do {                                                    \
    const bf16* _bt = wctf + (size_t)(t) * 6144;                                \
    unsigned _d = (unsigned)(buf) * 12288u;                                     \
    _Pragma("unroll")                                                           \
    for (int q = 0; q < 3; ++q)                                                 \
      gld16(smem + _d + (unsigned)(q * 256 + tid) * 16u,                        \
            _bt + (size_t)(q * 256 + tid) * 8);                                 \
  } while (0)

#define LOAD_A(Pa, Pb, Pc, Pd, T) do {                                          \
    const int _k = (T) * 32;                                                    \
    const float* _p0 = (_k < 8192) ? (a0x + _k) : (a0h + (_k - 8192));          \
    const float* _p1 = (_k < 8192) ? (a1x + _k) : (a1h + (_k - 8192));          \
    asm volatile("global_load_dwordx4 %0, %1, off"           : "=v"(Pa.u) : "v"(_p0)); \
    asm volatile("global_load_dwordx4 %0, %1, off offset:16" : "=v"(Pb.u) : "v"(_p0)); \
    asm volatile("global_load_dwordx4 %0, %1, off"           : "=v"(Pc.u) : "v"(_p1)); \
    asm volatile("global_load_dwordx4 %0, %1, off offset:16" : "=v"(Pd.u) : "v"(_p1)); \
  } while (0)

  f32x4 acc0[12] = {};
  f32x4 acc1[12] = {};
  F4 p00, p01, p10, p11, q00, q01, q10, q11;

  const unsigned ldsbase = (unsigned)(uintptr_t)&smem[0];
  const unsigned bB = (unsigned)lane * 16u;

  // prologue (matches steady-state issue order): B(0), B(1), A(0)
  STAGE_B(0, t_lo);
  if (nt > 1) STAGE_B(1, t_lo + 1);
  LOAD_A(p00, p01, p10, p11, t_lo);

  int b3r = 0, b3w = 2;   // i % 3, (i+2) % 3

#define GBODY(Ca, Cb, Cc, Cd, Na, Nb, Nc, Nd, I) do {                           \
    const int _i = (I);                                                         \
    if (_i + 2 < nt) STAGE_B(b3w, t_lo + _i + 2);           /* 3 DMA */         \
    if (_i + 1 < nt) LOAD_A(Na, Nb, Nc, Nd, t_lo + _i + 1); /* 4 reg */         \
    /* queue old->new: B(i), B(i+1), A(i), B(i+2), A(i+1); need A(i),B(i) */    \
    if (_i + 2 < nt)      asm volatile("s_waitcnt vmcnt(7)" ::: "memory");      \
    else if (_i + 1 < nt) asm volatile("s_waitcnt vmcnt(4)" ::: "memory");      \
    else                  asm volatile("s_waitcnt vmcnt(0)" ::: "memory");      \
    asm volatile("s_barrier" ::: "memory");   /* all waves: B(i) in LDS */      \
    {                                                                           \
      const unsigned _br = ldsbase + bB + (unsigned)b3r * 12288u;               \
      F4 _bv[12];                                                               \
      _Pragma("unroll")                                                         \
      for (int nf = 0; nf < 12; ++nf)                                           \
        asm volatile("ds_read_b128 %0, %1 offset:%c2"                           \
                     : "=v"(_bv[nf].u) : "v"(_br), "i"(nf * 1024));             \
      asm volatile("s_waitcnt lgkmcnt(0)" ::: "memory");                        \
      __builtin_amdgcn_sched_barrier(0);                                        \
      bf16x8 _af0 = pack8(Ca.f, Cb.f);                                          \
      bf16x8 _af1 = pack8(Cc.f, Cd.f);                                          \
      _Pragma("unroll")                                                         \
      for (int nf = 0; nf < 12; ++nf) {                                         \
        acc0[nf] = __builtin_amdgcn_mfma_f32_16x16x32_bf16(_af0, _bv[nf].h, acc0[nf], 0, 0, 0); \
        acc1[nf] = __builtin_amdgcn_mfma_f32_16x16x32_bf16(_af1, _bv[nf].h, acc1[nf], 0, 0, 0); \
      }                                                                         \
    }                                                                           \
    asm volatile("s_barrier" ::: "memory");   /* readers done before overwrite */\
    b3r = (b3r == 2) ? 0 : b3r + 1;                                             \
    b3w = (b3w == 2) ? 0 : b3w + 1;                                             \
  } while (0)

  int it = 0;
  for (; it + 1 < nt; it += 2) {
    GBODY(p00, p01, p10, p11, q00, q01, q10, q11, it);
    GBODY(q00, q01, q10, q11, p00, p01, p10, p11, it + 1);
  }
  if (it < nt) GBODY(p00, p01, p10, p11, q00, q01, q10, q11, it);
#undef GBODY
#undef LOAD_A
#undef STAGE_B

  // C/D layout (HW-verified): col = lane&15, row = (lane>>4)*4 + reg
  if (h1d) {  // direct mode (ksplit==1)
#pragma unroll
    for (int nf = 0; nf < 12; ++nf) {
      int col = nf * 16 + rl;
#pragma unroll
      for (int tt = 0; tt < 4; ++tt) {
        int ra = m0 + w * 32 + g * 4 + tt;
        int rb = ra + 16;
        if (col < 128) {
          h1d[(size_t)ra * 128 + col] = __float2bfloat16(acc0[nf][tt]);
          h1d[(size_t)rb * 128 + col] = __float2bfloat16(acc1[nf][tt]);
        } else {
          hx2d[(size_t)ra * 64 + (col - 128)] = acc0[nf][tt];
          hx2d[(size_t)rb * 64 + (col - 128)] = acc1[nf][tt];
        }
      }
    }
  } else {
    float* ypc = yp + (size_t)chunk * ((size_t)NNODES * NCOL);
#pragma unroll
    for (int nf = 0; nf < 12; ++nf) {
      int col = nf * 16 + rl;
#pragma unroll
      for (int tt = 0; tt < 4; ++tt) {
        int ra = m0 + w * 32 + g * 4 + tt;
        ypc[(size_t)ra * NCOL + col] = acc0[nf][tt];
        ypc[(size_t)(ra + 16) * NCOL + col] = acc1[nf][tt];
      }
    }
  }
}

// sum K-split partials (float4-vectorized); h1 -> bf16, hx2 -> fp32
__global__ void k_reduce4(const float* __restrict__ yp, bf16* __restrict__ h1,
                          float* __restrict__ hx2, int nch) {
  int u = blockIdx.x * 256 + threadIdx.x;      // < 8192*192/4
  float4 s = {0.f, 0.f, 0.f, 0.f};
  for (int c = 0; c < nch; c++) {
    float4 v = *(const float4*)(yp + (size_t)c * ((size_t)NNODES * NCOL) + (size_t)u * 4);
    s.x += v.x; s.y += v.y; s.z += v.z; s.w += v.w;
  }
  int e = u * 4;
  int i = e / NCOL, c = e - i * NCOL;          // float4 never straddles boundaries
  if (c < 128) {
    bf16* dst = h1 + (size_t)i * 128 + c;
    dst[0] = __float2bfloat16(s.x); dst[1] = __float2bfloat16(s.y);
    dst[2] = __float2bfloat16(s.z); dst[3] = __float2bfloat16(s.w);
  } else {
    *(float4*)(hx2 + (size_t)i * 64 + (c - 128)) = s;
  }
}

__device__ __forceinline__ float bflo(unsigned v) { return __uint_as_float(v << 16); }
__device__ __forceinline__ float bfhi(unsigned v) { return __uint_as_float(v & 0xffff0000u); }

__global__ void k_scat1(const bf16* __restrict__ h1b, const int* __restrict__ offs,
                        const int* __restrict__ csr, const float* __restrict__ dinv,
                        const float* __restrict__ b1, float* __restrict__ ru) {
  int node = blockIdx.x * 4 + (threadIdx.x >> 6);
  int lane = threadIdx.x & 63;
  const unsigned* h1u = (const unsigned*)h1b;
  float dd = dinv[node];
  unsigned vv = h1u[(size_t)node * 64 + lane];
  float ax = bflo(vv) * dd * dd, ay = bfhi(vv) * dd * dd;
  int e0 = offs[node], e1 = offs[node + 1];
  for (int e = e0; e < e1; ++e) {
    int s = csr[e];
    float nrm = dinv[s] * dd;
    unsigned wv = h1u[(size_t)s * 64 + lane];
    ax += bflo(wv) * nrm;
    ay += bfhi(wv) * nrm;
  }
  ax += b1[lane * 2];
  ay += b1[lane * 2 + 1];
  ax = 1.f / (1.f + expf(-ax));
  ay = 1.f / (1.f + expf(-ay));
  ru[(size_t)node * 128 + lane * 2]     = ax;
  ru[(size_t)node * 128 + lane * 2 + 1] = ay;
}

__global__ void k_rh(const float* __restrict__ ru, const float* __restrict__ hidden,
                     const float* __restrict__ hx2, const float* __restrict__ W2,
                     bf16* __restrict__ h2) {
  __shared__ float W2s[64][64];
  __shared__ float rhs[4][64];
  int tid = threadIdx.x;
#pragma unroll
  for (int t = 0; t < 16; ++t) {
    int idx = tid + 256 * t;
    int j = idx >> 6, c = idx & 63;
    W2s[j][c] = W2[(size_t)(8192 + j) * 64 + c];
  }
  int w = tid >> 6, lane = tid & 63;
  int i = blockIdx.x * 4 + w;
  float rv = ru[(size_t)(i >> 1) * 128 + ((i & 1) << 6) + lane];
  float hv = hidden[(size_t)i * 64 + lane];
  rhs[w][lane] = rv * hv;
  __syncthreads();
  float acc = hx2[(size_t)i * 64 + lane];
#pragma unroll 8
  for (int j = 0; j < 64; ++j) acc += rhs[w][j] * W2s[j][lane];
  h2[(size_t)i * 64 + lane] = __float2bfloat16(acc);
}

__global__ void k_scat2(const bf16* __restrict__ h2b, const int* __restrict__ offs,
                        const int* __restrict__ csr, const float* __restrict__ dinv,
                        const float* __restrict__ b2, const float* __restrict__ ru,
                        const float* __restrict__ hidden, float* __restrict__ out) {
  int node = blockIdx.x * 4 + (threadIdx.x >> 6);
  int lane = threadIdx.x & 63;
  const unsigned short* h2u = (const unsigned short*)h2b;
  float dd = dinv[node];
  float acc = bflo((unsigned)h2u[(size_t)node * 64 + lane]) * dd * dd;
  int e0 = offs[node], e1 = offs[node + 1];
  for (int e = e0; e < e1; ++e) {
    int s = csr[e];
    acc += bflo((unsigned)h2u[(size_t)s * 64 + lane]) * dinv[s] * dd;
  }
  acc += b2[lane];
  float cv = tanhf(acc);
  float u = ru[(size_t)(4096 + (node >> 1)) * 128 + ((node & 1) << 6) + lane];
  float hv = hidden[(size_t)node * 64 + lane];
  out[(size_t)node * 64 + lane] = u * hv + (1.f - u) * cv;
}

extern "C" void kernel_launch(void* const* d_in, const int* in_sizes, int n_in,
                              void* d_out, int out_size, void* d_ws, size_t ws_size,
                              hipStream_t stream) {
  (void)n_in; (void)out_size;
  const float* x   = (const float*)d_in[0];
  const float* hid = (const float*)d_in[1];
  const float* W1  = (const float*)d_in[2];
  const float* b1  = (const float*)d_in[3];
  const float* W2  = (const float*)d_in[4];
  const float* b2  = (const float*)d_in[5];
  const int*   ei  = (const int*)d_in[6];
  const int E = in_sizes[6] / 2;
  float* out = (float*)d_out;

  int ksplit;
  if      (ws_size >= YP_OFF + 8ull * YP_SLICE) ksplit = 8;
  else if (ws_size >= YP_OFF + 4ull * YP_SLICE) ksplit = 4;
  else if (ws_size >= YP_OFF + 2ull * YP_SLICE) ksplit = 2;
  else if (ws_size >= YP_OFF)                   ksplit = 1;
  else {
    k_out_zero<<<dim3(NNODES * 64 / 256), dim3(256), 0, stream>>>(out);
    return;
  }
  const int tpc = (KT32 + ksplit - 1) / ksplit;

  char* ws = (char*)d_ws;
  bf16*  wctf = (bf16*)(ws + WCT_OFF);
  int*   cnt  = (int*)(ws + CNT_OFF);
  int*   offs = (int*)(ws + OFF_OFF);
  int*   cur  = (int*)(ws + CUR_OFF);
  float* dinv = (float*)(ws + DNV_OFF);
  int*   csr  = (int*)(ws + CSR_OFF);
  bf16*  h1   = (bf16*)(ws + H1_OFF);
  float* hx2  = (float*)(ws + HX2_OFF);
  float* ru   = (float*)(ws + RU_OFF);
  bf16*  h2   = (bf16*)(ws + H2_OFF);
  float* yp   = (float*)(ws + YP_OFF);

  k_zero_i<<<dim3(32), dim3(256), 0, stream>>>(cnt, NNODES);
  k_prep_wctf<<<dim3((KT32 * 12 * 64 + 255) / 256), dim3(256), 0, stream>>>(W1, W2, wctf);
  k_hist<<<dim3((E + 255) / 256), dim3(256), 0, stream>>>(ei, E, cnt);
  k_scan<<<dim3(1), dim3(256), 0, stream>>>(cnt, offs, cur, dinv);
  k_fill<<<dim3((E + 255) / 256), dim3(256), 0, stream>>>(ei, E, cur, csr);
  if (ksplit == 1) {
    k_gemm<<<dim3(NNODES / BMB, 1), dim3(256), 0, stream>>>(x, hid, wctf, nullptr, h1, hx2, tpc);
  } else {
    k_gemm<<<dim3(NNODES / BMB, ksplit), dim3(256), 0, stream>>>(x, hid, wctf, yp, nullptr, nullptr, tpc);
    k_reduce4<<<dim3(NNODES * NCOL / 1024), dim3(256), 0, stream>>>(yp, h1, hx2, ksplit);
  }
  k_scat1<<<dim3(NNODES / 4), dim3(256), 0, stream>>>(h1, offs, csr, dinv, b1, ru);
  k_rh<<<dim3(NNODES / 4), dim3(256), 0, stream>>>(ru, hid, hx2, W2, h2);
  k_scat2<<<dim3(NNODES / 4), dim3(256), 0, stream>>>(h2, offs, csr, dinv, b2, ru, hid, out);
}

// Round 18
// 194.140 us; speedup vs baseline: 1.0788x; 1.0788x over previous
//
#include <hip/hip_runtime.h>
#include <hip/hip_bf16.h>
#include <stdint.h>

typedef __bf16 bf16x8 __attribute__((ext_vector_type(8)));
typedef float  f32x4  __attribute__((ext_vector_type(4)));
typedef unsigned uint4v __attribute__((ext_vector_type(4)));
using bf16 = __hip_bfloat16;

#define NNODES 8192
#define FIN    8256      // 8192 + 64
#define NCOL   192       // 128 (W1) + 64 (W2 top)
#define KT32   258       // 8256 / 32
#define BMB    128       // rows per block (4 waves x 32 rows each)

// ---- workspace layout (bytes) ----
enum : size_t {
  WCT_OFF  = 0,            // bf16 wctf [258][12][64][8]  3,170,304
  CNT_OFF  = 3170304,      // int  [8192]
  OFF_OFF  = 3203072,      // int  [8193]
  CUR_OFF  = 3236096,      // int  [8192]
  DNV_OFF  = 3268864,      // f32  [8192]
  CSR_OFF  = 3301632,      // int  [262144]
  H1_OFF   = 4350208,      // bf16 [8192][128]
  HX2_OFF  = 8544512,      // f32  [8192][64]
  RU_OFF   = 10641664,     // f32  [8192][128]
  H2_OFF   = 14835968,     // bf16 [8192][64]
  YP_OFF   = 16933120,     // f32  [ksplit][8192][192]
  YP_SLICE = 6291456
};

__global__ void k_zero_i(int* p, int n) {
  int i = blockIdx.x * 256 + threadIdx.x;
  if (i < n) p[i] = 0;
}

__global__ void k_out_zero(float* out) {
  int i = blockIdx.x * 256 + threadIdx.x;
  if (i < NNODES * 64) out[i] = 0.f;   // diagnostic signature if ws too small
}

// Fragment-packed B build, COALESCED: one block per K-tile t. Stage W1 rows
// (32x128 f32) + W2 rows (32x64 f32) into LDS via float4, then emit
// wctf[t][nf][lane][8] with contiguous uint4 writes.
// wctf[(t*768 + nf*64 + lane)*8 + j] = Wc[t*32 + (lane>>4)*8 + j][nf*16 + (lane&15)]
__global__ __launch_bounds__(256) void k_prep_wctf(const float* __restrict__ W1,
                                                   const float* __restrict__ W2,
                                                   bf16* __restrict__ wctf) {
  __shared__ float W1s[32][128];   // 16 KB
  __shared__ float W2s[32][64];    //  8 KB
  const int t = blockIdx.x;        // 0..257
  const int k0 = t * 32;
  const int tid = threadIdx.x;
  // W1: 32 rows x 32 float4 = 1024 float4; 4 per thread (coalesced)
#pragma unroll
  for (int q = 0; q < 4; ++q) {
    int idx = tid + 256 * q;            // 0..1023
    int r = idx >> 5, c4 = idx & 31;
    float4 v = *(const float4*)(W1 + (size_t)(k0 + r) * 128 + c4 * 4);
    *(float4*)&W1s[r][c4 * 4] = v;
  }
  // W2: 32 rows x 16 float4 = 512 float4; 2 per thread (rows valid only if k<8192)
#pragma unroll
  for (int q = 0; q < 2; ++q) {
    int idx = tid + 256 * q;            // 0..511
    int r = idx >> 4, c4 = idx & 15;
    float4 v = {0.f, 0.f, 0.f, 0.f};
    if (k0 + r < 8192) v = *(const float4*)(W2 + (size_t)(k0 + r) * 64 + c4 * 4);
    *(float4*)&W2s[r][c4 * 4] = v;
  }
  __syncthreads();
  // emit 768 uint4; 3 per thread, contiguous
#pragma unroll
  for (int q = 0; q < 3; ++q) {
    int gl = tid + 256 * q;             // 0..767
    int nf = gl >> 6, lane = gl & 63;
    int col = nf * 16 + (lane & 15);
    int kk = (lane >> 4) * 8;
    union { bf16 h[8]; uint4 v; } u;
#pragma unroll
    for (int j = 0; j < 8; ++j) {
      float v = (col < 128) ? W1s[kk + j][col] : W2s[kk + j][col - 128];
      u.h[j] = __float2bfloat16(v);
    }
    *(uint4*)(wctf + ((size_t)t * 768 + gl) * 8) = u.v;
  }
}

__global__ void k_hist(const int* __restrict__ ei, int E, int* cnt) {
  int e = blockIdx.x * 256 + threadIdx.x;
  if (e < E) atomicAdd(&cnt[ei[E + e]], 1);
}

__global__ void k_scan(const int* __restrict__ cnt, int* __restrict__ offs,
                       int* __restrict__ cur, float* __restrict__ dinv) {
  __shared__ int part[256];
  int tid = threadIdx.x;
  int base = tid * 32;
  int s = 0;
#pragma unroll
  for (int j = 0; j < 32; j++) s += cnt[base + j];
  part[tid] = s;
  __syncthreads();
  for (int off = 1; off < 256; off <<= 1) {
    int a = (tid >= off) ? part[tid - off] : 0;
    __syncthreads();
    part[tid] += a;
    __syncthreads();
  }
  int run = (tid == 0) ? 0 : part[tid - 1];
  for (int j = 0; j < 32; j++) {
    int c = cnt[base + j];
    offs[base + j] = run;
    cur[base + j]  = run;
    dinv[base + j] = rsqrtf((float)(c + 1));
    run += c;
  }
  if (tid == 255) offs[NNODES] = run;
}

__global__ void k_fill(const int* __restrict__ ei, int E, int* cur, int* __restrict__ csr) {
  int e = blockIdx.x * 256 + threadIdx.x;
  if (e < E) {
    int d = ei[E + e];
    int p = atomicAdd(&cur[d], 1);
    csr[p] = ei[e];
  }
}

__device__ __forceinline__ bf16x8 pack8(float4 a, float4 b) {
  union { bf16 h[8]; bf16x8 v; } u;
  u.h[0] = __float2bfloat16(a.x); u.h[1] = __float2bfloat16(a.y);
  u.h[2] = __float2bfloat16(a.z); u.h[3] = __float2bfloat16(a.w);
  u.h[4] = __float2bfloat16(b.x); u.h[5] = __float2bfloat16(b.y);
  u.h[6] = __float2bfloat16(b.z); u.h[7] = __float2bfloat16(b.w);
  return u.v;
}

union F4 { uint4v u; float4 f; bf16x8 h; };

__device__ __forceinline__ void gld16(void* ldsdst, const void* gsrc) {
  __builtin_amdgcn_global_load_lds(
      (__attribute__((address_space(1))) void*)gsrc,
      (__attribute__((address_space(3))) void*)ldsdst, 16, 0, 0);
}

// C = [x | hidden] @ Wc : M=8192, N=192, K=8256  (R17 structure, passing)
// A: global->register (asm, P/Q ping-pong). B: triple-buffered LDS via
// global_load_lds, counted per-thread vmcnt (7/4/0), asm s_barrier.
__global__ __launch_bounds__(256, 2) void k_gemm(const float* __restrict__ x,
                                                 const float* __restrict__ hid,
                                                 const bf16* __restrict__ wctf,
                                                 float* __restrict__ yp,
                                                 bf16* __restrict__ h1d,
                                                 float* __restrict__ hx2d,
                                                 int tpc) {
  __shared__ __align__(1024) unsigned char smem[36864];  // B: 3 x 12KB
  const int tid = threadIdx.x;
  const int lane = tid & 63, w = tid >> 6;
  const int rl = lane & 15, g = lane >> 4;
  const int m0 = blockIdx.x * BMB;
  const int r0 = m0 + w * 32 + rl, r1 = r0 + 16;
  const int chunk = blockIdx.y;
  const int t_lo = chunk * tpc;
  const int t_hi = (t_lo + tpc > KT32) ? KT32 : (t_lo + tpc);
  const int nt = t_hi - t_lo;
  if (nt <= 0) return;

  const float* a0x = x + (size_t)r0 * 8192 + g * 8;
  const float* a1x = x + (size_t)r1 * 8192 + g * 8;
  const float* a0h = hid + (size_t)r0 * 64 + g * 8;
  const float* a1h = hid + (size_t)r1 * 64 + g * 8;

#define STAGE_B(buf, t) do {                                                    \
    const bf16* _bt = wctf + (size_t)(t) * 6144;                                \
    unsigned _d = (unsigned)(buf) * 12288u;                                     \
    _Pragma("unroll")                                                           \
    for (int q = 0; q < 3; ++q)                                                 \
      gld16(smem + _d + (unsigned)(q * 256 + tid) * 16u,                        \
            _bt + (size_t)(q * 256 + tid) * 8);                                 \
  } while (0)

#define LOAD_A(Pa, Pb, Pc, Pd, T) do {                                          \
    const int _k = (T) * 32;                                                    \
    const float* _p0 = (_k < 8192) ? (a0x + _k) : (a0h + (_k - 8192));          \
    const float* _p1 = (_k < 8192) ? (a1x + _k) : (a1h + (_k - 8192));          \
    asm volatile("global_load_dwordx4 %0, %1, off"           : "=v"(Pa.u) : "v"(_p0)); \
    asm volatile("global_load_dwordx4 %0, %1, off offset:16" : "=v"(Pb.u) : "v"(_p0)); \
    asm volatile("global_load_dwordx4 %0, %1, off"           : "=v"(Pc.u) : "v"(_p1)); \
    asm volatile("global_load_dwordx4 %0, %1, off offset:16" : "=v"(Pd.u) : "v"(_p1)); \
  } while (0)

  f32x4 acc0[12] = {};
  f32x4 acc1[12] = {};
  F4 p00, p01, p10, p11, q00, q01, q10, q11;

  const unsigned ldsbase = (unsigned)(uintptr_t)&smem[0];
  const unsigned bB = (unsigned)lane * 16u;

  // prologue (matches steady-state issue order): B(0), B(1), A(0)
  STAGE_B(0, t_lo);
  if (nt > 1) STAGE_B(1, t_lo + 1);
  LOAD_A(p00, p01, p10, p11, t_lo);

  int b3r = 0, b3w = 2;   // i % 3, (i+2) % 3

#define GBODY(Ca, Cb, Cc, Cd, Na, Nb, Nc, Nd, I) do {                           \
    const int _i = (I);                                                         \
    if (_i + 2 < nt) STAGE_B(b3w, t_lo + _i + 2);           /* 3 DMA */         \
    if (_i + 1 < nt) LOAD_A(Na, Nb, Nc, Nd, t_lo + _i + 1); /* 4 reg */         \
    /* queue old->new: B(i), B(i+1), A(i), B(i+2), A(i+1); need A(i),B(i) */    \
    if (_i + 2 < nt)      asm volatile("s_waitcnt vmcnt(7)" ::: "memory");      \
    else if (_i + 1 < nt) asm volatile("s_waitcnt vmcnt(4)" ::: "memory");      \
    else                  asm volatile("s_waitcnt vmcnt(0)" ::: "memory");      \
    asm volatile("s_barrier" ::: "memory");   /* all waves: B(i) in LDS */      \
    {                                                                           \
      const unsigned _br = ldsbase + bB + (unsigned)b3r * 12288u;               \
      F4 _bv[12];                                                               \
      _Pragma("unroll")                                                         \
      for (int nf = 0; nf < 12; ++nf)                                           \
        asm volatile("ds_read_b128 %0, %1 offset:%c2"                           \
                     : "=v"(_bv[nf].u) : "v"(_br), "i"(nf * 1024));             \
      asm volatile("s_waitcnt lgkmcnt(0)" ::: "memory");                        \
      __builtin_amdgcn_sched_barrier(0);                                        \
      bf16x8 _af0 = pack8(Ca.f, Cb.f);                                          \
      bf16x8 _af1 = pack8(Cc.f, Cd.f);                                          \
      _Pragma("unroll")                                                         \
      for (int nf = 0; nf < 12; ++nf) {                                         \
        acc0[nf] = __builtin_amdgcn_mfma_f32_16x16x32_bf16(_af0, _bv[nf].h, acc0[nf], 0, 0, 0); \
        acc1[nf] = __builtin_amdgcn_mfma_f32_16x16x32_bf16(_af1, _bv[nf].h, acc1[nf], 0, 0, 0); \
      }                                                                         \
    }                                                                           \
    asm volatile("s_barrier" ::: "memory");   /* readers done before overwrite */\
    b3r = (b3r == 2) ? 0 : b3r + 1;                                             \
    b3w = (b3w == 2) ? 0 : b3w + 1;                                             \
  } while (0)

  int it = 0;
  for (; it + 1 < nt; it += 2) {
    GBODY(p00, p01, p10, p11, q00, q01, q10, q11, it);
    GBODY(q00, q01, q10, q11, p00, p01, p10, p11, it + 1);
  }
  if (it < nt) GBODY(p00, p01, p10, p11, q00, q01, q10, q11, it);
#undef GBODY
#undef LOAD_A
#undef STAGE_B

  // C/D layout (HW-verified): col = lane&15, row = (lane>>4)*4 + reg
  if (h1d) {  // direct mode (ksplit==1)
#pragma unroll
    for (int nf = 0; nf < 12; ++nf) {
      int col = nf * 16 + rl;
#pragma unroll
      for (int tt = 0; tt < 4; ++tt) {
        int ra = m0 + w * 32 + g * 4 + tt;
        int rb = ra + 16;
        if (col < 128) {
          h1d[(size_t)ra * 128 + col] = __float2bfloat16(acc0[nf][tt]);
          h1d[(size_t)rb * 128 + col] = __float2bfloat16(acc1[nf][tt]);
        } else {
          hx2d[(size_t)ra * 64 + (col - 128)] = acc0[nf][tt];
          hx2d[(size_t)rb * 64 + (col - 128)] = acc1[nf][tt];
        }
      }
    }
  } else {
    float* ypc = yp + (size_t)chunk * ((size_t)NNODES * NCOL);
#pragma unroll
    for (int nf = 0; nf < 12; ++nf) {
      int col = nf * 16 + rl;
#pragma unroll
      for (int tt = 0; tt < 4; ++tt) {
        int ra = m0 + w * 32 + g * 4 + tt;
        ypc[(size_t)ra * NCOL + col] = acc0[nf][tt];
        ypc[(size_t)(ra + 16) * NCOL + col] = acc1[nf][tt];
      }
    }
  }
}

// sum K-split partials (float4-vectorized); h1 -> bf16, hx2 -> fp32
__global__ void k_reduce4(const float* __restrict__ yp, bf16* __restrict__ h1,
                          float* __restrict__ hx2, int nch) {
  int u = blockIdx.x * 256 + threadIdx.x;      // < 8192*192/4
  float4 s = {0.f, 0.f, 0.f, 0.f};
  for (int c = 0; c < nch; c++) {
    float4 v = *(const float4*)(yp + (size_t)c * ((size_t)NNODES * NCOL) + (size_t)u * 4);
    s.x += v.x; s.y += v.y; s.z += v.z; s.w += v.w;
  }
  int e = u * 4;
  int i = e / NCOL, c = e - i * NCOL;          // float4 never straddles boundaries
  if (c < 128) {
    bf16* dst = h1 + (size_t)i * 128 + c;
    dst[0] = __float2bfloat16(s.x); dst[1] = __float2bfloat16(s.y);
    dst[2] = __float2bfloat16(s.z); dst[3] = __float2bfloat16(s.w);
  } else {
    *(float4*)(hx2 + (size_t)i * 64 + (c - 128)) = s;
  }
}

__device__ __forceinline__ float bflo(unsigned v) { return __uint_as_float(v << 16); }
__device__ __forceinline__ float bfhi(unsigned v) { return __uint_as_float(v & 0xffff0000u); }

__global__ void k_scat1(const bf16* __restrict__ h1b, const int* __restrict__ offs,
                        const int* __restrict__ csr, const float* __restrict__ dinv,
                        const float* __restrict__ b1, float* __restrict__ ru) {
  int node = blockIdx.x * 4 + (threadIdx.x >> 6);
  int lane = threadIdx.x & 63;
  const unsigned* h1u = (const unsigned*)h1b;
  float dd = dinv[node];
  unsigned vv = h1u[(size_t)node * 64 + lane];
  float ax = bflo(vv) * dd * dd, ay = bfhi(vv) * dd * dd;
  int e0 = offs[node], e1 = offs[node + 1];
  for (int e = e0; e < e1; ++e) {
    int s = csr[e];
    float nrm = dinv[s] * dd;
    unsigned wv = h1u[(size_t)s * 64 + lane];
    ax += bflo(wv) * nrm;
    ay += bfhi(wv) * nrm;
  }
  ax += b1[lane * 2];
  ay += b1[lane * 2 + 1];
  ax = 1.f / (1.f + expf(-ax));
  ay = 1.f / (1.f + expf(-ay));
  ru[(size_t)node * 128 + lane * 2]     = ax;
  ru[(size_t)node * 128 + lane * 2 + 1] = ay;
}

__global__ void k_rh(const float* __restrict__ ru, const float* __restrict__ hidden,
                     const float* __restrict__ hx2, const float* __restrict__ W2,
                     bf16* __restrict__ h2) {
  __shared__ float W2s[64][64];
  __shared__ float rhs[4][64];
  int tid = threadIdx.x;
#pragma unroll
  for (int t = 0; t < 16; ++t) {
    int idx = tid + 256 * t;
    int j = idx >> 6, c = idx & 63;
    W2s[j][c] = W2[(size_t)(8192 + j) * 64 + c];
  }
  int w = tid >> 6, lane = tid & 63;
  int i = blockIdx.x * 4 + w;
  float rv = ru[(size_t)(i >> 1) * 128 + ((i & 1) << 6) + lane];
  float hv = hidden[(size_t)i * 64 + lane];
  rhs[w][lane] = rv * hv;
  __syncthreads();
  float acc = hx2[(size_t)i * 64 + lane];
#pragma unroll 8
  for (int j = 0; j < 64; ++j) acc += rhs[w][j] * W2s[j][lane];
  h2[(size_t)i * 64 + lane] = __float2bfloat16(acc);
}

__global__ void k_scat2(const bf16* __restrict__ h2b, const int* __restrict__ offs,
                        const int* __restrict__ csr, const float* __restrict__ dinv,
                        const float* __restrict__ b2, const float* __restrict__ ru,
                        const float* __restrict__ hidden, float* __restrict__ out) {
  int node = blockIdx.x * 4 + (threadIdx.x >> 6);
  int lane = threadIdx.x & 63;
  const unsigned short* h2u = (const unsigned short*)h2b;
  float dd = dinv[node];
  float acc = bflo((unsigned)h2u[(size_t)node * 64 + lane]) * dd * dd;
  int e0 = offs[node], e1 = offs[node + 1];
  for (int e = e0; e < e1; ++e) {
    int s = csr[e];
    acc += bflo((unsigned)h2u[(size_t)s * 64 + lane]) * dinv[s] * dd;
  }
  acc += b2[lane];
  float cv = tanhf(acc);
  float u = ru[(size_t)(4096 + (node >> 1)) * 128 + ((node & 1) << 6) + lane];
  float hv = hidden[(size_t)node * 64 + lane];
  out[(size_t)node * 64 + lane] = u * hv + (1.f - u) * cv;
}

extern "C" void kernel_launch(void* const* d_in, const int* in_sizes, int n_in,
                              void* d_out, int out_size, void* d_ws, size_t ws_size,
                              hipStream_t stream) {
  (void)n_in; (void)out_size;
  const float* x   = (const float*)d_in[0];
  const float* hid = (const float*)d_in[1];
  const float* W1  = (const float*)d_in[2];
  const float* b1  = (const float*)d_in[3];
  const float* W2  = (const float*)d_in[4];
  const float* b2  = (const float*)d_in[5];
  const int*   ei  = (const int*)d_in[6];
  const int E = in_sizes[6] / 2;
  float* out = (float*)d_out;

  int ksplit;
  if      (ws_size >= YP_OFF + 12ull * YP_SLICE) ksplit = 12;
  else if (ws_size >= YP_OFF + 8ull  * YP_SLICE) ksplit = 8;
  else if (ws_size >= YP_OFF + 4ull  * YP_SLICE) ksplit = 4;
  else if (ws_size >= YP_OFF + 2ull  * YP_SLICE) ksplit = 2;
  else if (ws_size >= YP_OFF)                    ksplit = 1;
  else {
    k_out_zero<<<dim3(NNODES * 64 / 256), dim3(256), 0, stream>>>(out);
    return;
  }
  const int tpc = (KT32 + ksplit - 1) / ksplit;

  char* ws = (char*)d_ws;
  bf16*  wctf = (bf16*)(ws + WCT_OFF);
  int*   cnt  = (int*)(ws + CNT_OFF);
  int*   offs = (int*)(ws + OFF_OFF);
  int*   cur  = (int*)(ws + CUR_OFF);
  float* dinv = (float*)(ws + DNV_OFF);
  int*   csr  = (int*)(ws + CSR_OFF);
  bf16*  h1   = (bf16*)(ws + H1_OFF);
  float* hx2  = (float*)(ws + HX2_OFF);
  float* ru   = (float*)(ws + RU_OFF);
  bf16*  h2   = (bf16*)(ws + H2_OFF);
  float* yp   = (float*)(ws + YP_OFF);

  k_zero_i<<<dim3(32), dim3(256), 0, stream>>>(cnt, NNODES);
  k_prep_wctf<<<dim3(KT32), dim3(256), 0, stream>>>(W1, W2, wctf);
  k_hist<<<dim3((E + 255) / 256), dim3(256), 0, stream>>>(ei, E, cnt);
  k_scan<<<dim3(1), dim3(256), 0, stream>>>(cnt, offs, cur, dinv);
  k_fill<<<dim3((E + 255) / 256), dim3(256), 0, stream>>>(ei, E, cur, csr);
  if (ksplit == 1) {
    k_gemm<<<dim3(NNODES / BMB, 1), dim3(256), 0, stream>>>(x, hid, wctf, nullptr, h1, hx2, tpc);
  } else {
    k_gemm<<<dim3(NNODES / BMB, ksplit), dim3(256), 0, stream>>>(x, hid, wctf, yp, nullptr, nullptr, tpc);
    k_reduce4<<<dim3(NNODES * NCOL / 1024), dim3(256), 0, stream>>>(yp, h1, hx2, ksplit);
  }
  k_scat1<<<dim3(NNODES / 4), dim3(256), 0, stream>>>(h1, offs, csr, dinv, b1, ru);
  k_rh<<<dim3(NNODES / 4), dim3(256), 0, stream>>>(ru, hid, hx2, W2, h2);
  k_scat2<<<dim3(NNODES / 4), dim3(256), 0, stream>>>(h2, offs, csr, dinv, b2, ru, hid, out);
}